// Round 1
// baseline (618.397 us; speedup 1.0000x reference)
//
#include <hip/hip_runtime.h>
#include <cstdint>
#include <cstddef>

// Problem constants
#define B_   4
#define C_   2048      // seq / conv channels
#define DM_  128       // d_model / conv length
#define H_   8
#define KK_  14336     // C_ * 7  (im2col K dimension)
#define N_   512       // B_ * DM_ (GEMM N dimension)

typedef unsigned short u16;
typedef __attribute__((ext_vector_type(8))) short  s16x8;   // 8 x bf16 (4 VGPRs)
typedef __attribute__((ext_vector_type(4))) float  f32x4;

__device__ __forceinline__ u16 f2bf(float f) {
    uint32_t u = __builtin_bit_cast(uint32_t, f);
    u += 0x7fffu + ((u >> 16) & 1u);   // round-to-nearest-even
    return (u16)(u >> 16);
}
__device__ __forceinline__ uint32_t pk2(float a, float b) {
    return (uint32_t)f2bf(a) | ((uint32_t)f2bf(b) << 16);
}

// ---------------------------------------------------------------- zero
__global__ __launch_bounds__(256) void zero_f4(float4* __restrict__ p, int n4) {
    int i = blockIdx.x * 256 + threadIdx.x;
    if (i < n4) p[i] = make_float4(0.f, 0.f, 0.f, 0.f);
}

// ---------------------------------------------------------------- im2col^T prep
// BimT[n][k] = x[b][ci][l + t - 6] (0 if l+t-6 < 0), n = b*128+l, k = ci*7+t, bf16.
// Thread handles (n, ci-pair): 14 bf16 = 7 aligned dword stores, coalesced along cp.
__global__ __launch_bounds__(256) void prep_bimt(const float* __restrict__ key,
                                                 const float* __restrict__ value,
                                                 u16* __restrict__ bk,
                                                 u16* __restrict__ bv) {
    const float* src = blockIdx.z ? value : key;
    u16*         dst = blockIdx.z ? bv : bk;
    int gid = blockIdx.x * 256 + threadIdx.x;   // 0 .. 524287
    int cp = gid & 1023;                        // ci pair index
    int n  = gid >> 10;                         // 0 .. 511
    int b = n >> 7, l = n & 127;
    const float* s0 = src + (size_t)(b * C_ + cp * 2) * DM_;
    u16 hh[14];
#pragma unroll
    for (int r = 0; r < 2; ++r) {
#pragma unroll
        for (int t = 0; t < 7; ++t) {
            int j = l + t - 6;
            float v = (j >= 0) ? s0[r * DM_ + j] : 0.0f;
            hh[r * 7 + t] = f2bf(v);
        }
    }
    uint32_t* D = (uint32_t*)dst + (size_t)n * (KK_ / 2) + cp * 7;
#pragma unroll
    for (int i = 0; i < 7; ++i)
        D[i] = (uint32_t)hh[2 * i] | ((uint32_t)hh[2 * i + 1] << 16);
}

// ---------------------------------------------------------------- query prep (scale 1/4, bf16)
__global__ __launch_bounds__(256) void prep_q(const float4* __restrict__ q, uint2* __restrict__ qb) {
    int i = blockIdx.x * 256 + threadIdx.x;     // 0 .. 262143
    float4 v = q[i];
    uint2 r;
    r.x = pk2(v.x * 0.25f, v.y * 0.25f);
    r.y = pk2(v.z * 0.25f, v.w * 0.25f);
    qb[i] = r;
}

// ---------------------------------------------------------------- conv as GEMM
// Y[m=co][n=(b,l)] += sum_k W[m*14336+k] * BimT[n][k].  Tile 64M x 256N, split-K=4.
// grid: x=32 Mtiles, y=2 Ntiles, z=8 (conv*4 + splitk)
__global__ __launch_bounds__(256, 2) void conv_gemm(
        const float* __restrict__ Wk, const float* __restrict__ Wv,
        const u16* __restrict__ Bk, const u16* __restrict__ Bv,
        float* __restrict__ Yk, float* __restrict__ Yv) {
    const int conv = blockIdx.z >> 2;
    const int sk   = blockIdx.z & 3;
    const float* W  = conv ? Wv : Wk;
    const u16*   Bm = conv ? Bv : Bk;
    float*       Y  = conv ? Yv : Yk;
    const int m0 = blockIdx.x * 64;
    const int n0 = blockIdx.y * 256;
    const int kbeg = sk * 3584;

    __shared__ __align__(16) u16 Al[64 * 40];     // 64 rows x 32 bf16 (+pad), stride 80 B
    __shared__ __align__(16) u16 Bl[256 * 40];    // 256 rows x 32 bf16 (+pad)

    const int tid = threadIdx.x;
    const int wave = tid >> 6, lane = tid & 63;
    const int l16 = lane & 15, quad = lane >> 4;
    const int wn0 = wave * 64;

    f32x4 acc[4][4];
#pragma unroll
    for (int i = 0; i < 4; ++i)
#pragma unroll
        for (int j = 0; j < 4; ++j) acc[i][j] = (f32x4){0.f, 0.f, 0.f, 0.f};

    const int arow = tid >> 2, aseg = tid & 3;
    const float* wp = W  + (size_t)(m0 + arow) * KK_ + kbeg + aseg * 8;
    const u16*   bp = Bm + (size_t)(n0 + tid)  * KK_ + kbeg;
    u16* aw = &Al[arow * 40 + aseg * 8];
    u16* bw = &Bl[tid * 40];

    for (int ks = 0; ks < 112; ++ks) {
        __syncthreads();
        float4 f0 = *(const float4*)(wp);
        float4 f1 = *(const float4*)(wp + 4);
        uint4 pa;
        pa.x = pk2(f0.x, f0.y); pa.y = pk2(f0.z, f0.w);
        pa.z = pk2(f1.x, f1.y); pa.w = pk2(f1.z, f1.w);
        uint4 b0 = *(const uint4*)(bp);
        uint4 b1 = *(const uint4*)(bp + 8);
        uint4 b2 = *(const uint4*)(bp + 16);
        uint4 b3 = *(const uint4*)(bp + 24);
        *(uint4*)aw = pa;
        *(uint4*)(bw)      = b0;
        *(uint4*)(bw + 8)  = b1;
        *(uint4*)(bw + 16) = b2;
        *(uint4*)(bw + 24) = b3;
        __syncthreads();

        s16x8 af[4], bf[4];
#pragma unroll
        for (int fm = 0; fm < 4; ++fm)
            af[fm] = *(const s16x8*)&Al[(fm * 16 + l16) * 40 + quad * 8];
#pragma unroll
        for (int fn = 0; fn < 4; ++fn)
            bf[fn] = *(const s16x8*)&Bl[(wn0 + fn * 16 + l16) * 40 + quad * 8];
#pragma unroll
        for (int fm = 0; fm < 4; ++fm)
#pragma unroll
            for (int fn = 0; fn < 4; ++fn)
                acc[fm][fn] = __builtin_amdgcn_mfma_f32_16x16x32_bf16(af[fm], bf[fn], acc[fm][fn], 0, 0, 0);
        wp += 32;
        bp += 32;
    }

    // epilogue: split-K accumulate. C layout: col = lane&15, row = quad*4 + reg.
#pragma unroll
    for (int fm = 0; fm < 4; ++fm) {
        int m = m0 + fm * 16 + quad * 4;
#pragma unroll
        for (int fn = 0; fn < 4; ++fn) {
            int n = n0 + wn0 + fn * 16 + l16;
            int bb = n >> 7, ll = n & 127;
            float* yp = Y + ((size_t)(bb * C_ + m)) * DM_ + ll;
#pragma unroll
            for (int r = 0; r < 4; ++r)
                atomicAdd(yp + (size_t)r * DM_, acc[fm][fn][r]);
        }
    }
}

// ---------------------------------------------------------------- flash attention
// grid: x = 32 q-tiles (64 rows), y = 32 (b*8+h). Block 256 = 4 waves; wave owns 16 q-rows.
__global__ __launch_bounds__(256, 4) void attn_k(
        const float* __restrict__ Yk, const float* __restrict__ Yv,
        const float* __restrict__ bkb, const float* __restrict__ bvb,
        const u16* __restrict__ qb, u16* __restrict__ att) {
    const int q0 = blockIdx.x * 64;
    const int bh = blockIdx.y;
    const int b = bh >> 3, h = bh & 7;

    __shared__ __align__(16) u16 Kl[128 * 40];   // key rows x d(0..15 real, rest unused), stride 80 B
    __shared__ __align__(16) u16 Vl[128 * 20];   // key rows x 16 d, stride 40 B
    __shared__ __align__(16) u16 Pl[64 * 136];   // q rows x 128 keys, stride 272 B

    const int tid = threadIdx.x;
    const int wave = tid >> 6, lane = tid & 63;
    const int l16 = lane & 15, quad = lane >> 4;
    const float LOG2E = 1.44269504088896340736f;

    // Q fragment (A-layout): m = lane&15, k(d) = quad*8+j ; d>=16 is zero padding.
    s16x8 qf = {};
    if (quad < 2) {
        const u16* qp = qb + ((size_t)(b * C_ + q0 + wave * 16 + l16)) * DM_ + h * 16 + quad * 8;
        qf = *(const s16x8*)qp;
    }
    f32x4 o = (f32x4){0.f, 0.f, 0.f, 0.f};
    float mr[4] = {-3e38f, -3e38f, -3e38f, -3e38f};
    float lr[4] = {0.f, 0.f, 0.f, 0.f};

    const int srow = tid >> 1, shalf = tid & 1;

    for (int kt = 0; kt < 16; ++kt) {
        const int k0 = kt * 128;
        __syncthreads();
        {   // stage K tile and V tile (fp32 + bias -> bf16)
            size_t base = ((size_t)(b * C_ + k0 + srow)) * DM_ + h * 16 + shalf * 8;
            float kb_ = bkb[k0 + srow];
            float4 a0 = *(const float4*)(Yk + base);
            float4 a1 = *(const float4*)(Yk + base + 4);
            uint4 pkk;
            pkk.x = pk2(a0.x + kb_, a0.y + kb_); pkk.y = pk2(a0.z + kb_, a0.w + kb_);
            pkk.z = pk2(a1.x + kb_, a1.y + kb_); pkk.w = pk2(a1.z + kb_, a1.w + kb_);
            *(uint4*)&Kl[srow * 40 + shalf * 8] = pkk;

            float vb_ = bvb[k0 + srow];
            float4 v0 = *(const float4*)(Yv + base);
            float4 v1 = *(const float4*)(Yv + base + 4);
            uint2 u0, u1;
            u0.x = pk2(v0.x + vb_, v0.y + vb_); u0.y = pk2(v0.z + vb_, v0.w + vb_);
            u1.x = pk2(v1.x + vb_, v1.y + vb_); u1.y = pk2(v1.z + vb_, v1.w + vb_);
            *(uint2*)&Vl[srow * 20 + shalf * 8]     = u0;
            *(uint2*)&Vl[srow * 20 + shalf * 8 + 4] = u1;
        }
        __syncthreads();

        // S = Q K^T : 8 N-frags of 16 keys
        f32x4 sf[8];
#pragma unroll
        for (int fn = 0; fn < 8; ++fn) {
            s16x8 kb = {};
            if (quad < 2) kb = *(const s16x8*)&Kl[(fn * 16 + l16) * 40 + quad * 8];
            sf[fn] = __builtin_amdgcn_mfma_f32_16x16x32_bf16(qf, kb, (f32x4){0.f, 0.f, 0.f, 0.f}, 0, 0, 0);
        }

        // online softmax: lane holds rows quad*4+r, cols l16 + 16*fn
        float mt[4];
#pragma unroll
        for (int r = 0; r < 4; ++r) {
            float m = sf[0][r];
#pragma unroll
            for (int fn = 1; fn < 8; ++fn) m = fmaxf(m, sf[fn][r]);
            m = fmaxf(m, __shfl_xor(m, 1));
            m = fmaxf(m, __shfl_xor(m, 2));
            m = fmaxf(m, __shfl_xor(m, 4));
            m = fmaxf(m, __shfl_xor(m, 8));
            mt[r] = m;
        }
        float al[4], ps[4];
#pragma unroll
        for (int r = 0; r < 4; ++r) {
            float mnew = fmaxf(mr[r], mt[r]);
            al[r] = exp2f((mr[r] - mnew) * LOG2E);
            mr[r] = mnew;
            ps[r] = 0.f;
        }
#pragma unroll
        for (int fn = 0; fn < 8; ++fn) {
#pragma unroll
            for (int r = 0; r < 4; ++r) {
                float p = exp2f((sf[fn][r] - mr[r]) * LOG2E);
                ps[r] += p;
                Pl[(wave * 16 + quad * 4 + r) * 136 + fn * 16 + l16] = f2bf(p);
            }
        }
#pragma unroll
        for (int r = 0; r < 4; ++r) {
            float t = ps[r];
            t += __shfl_xor(t, 1);
            t += __shfl_xor(t, 2);
            t += __shfl_xor(t, 4);
            t += __shfl_xor(t, 8);
            lr[r] = lr[r] * al[r] + t;
            o[r] *= al[r];
        }
        __syncthreads();

        // O += P V  (K-dim = 128 keys, 4 MFMAs)
#pragma unroll
        for (int ko = 0; ko < 4; ++ko) {
            s16x8 pa = *(const s16x8*)&Pl[(wave * 16 + l16) * 136 + ko * 32 + quad * 8];
            uint4 vv;
            {
                u16 e0 = Vl[(ko * 32 + quad * 8 + 0) * 20 + l16];
                u16 e1 = Vl[(ko * 32 + quad * 8 + 1) * 20 + l16];
                u16 e2 = Vl[(ko * 32 + quad * 8 + 2) * 20 + l16];
                u16 e3 = Vl[(ko * 32 + quad * 8 + 3) * 20 + l16];
                u16 e4 = Vl[(ko * 32 + quad * 8 + 4) * 20 + l16];
                u16 e5 = Vl[(ko * 32 + quad * 8 + 5) * 20 + l16];
                u16 e6 = Vl[(ko * 32 + quad * 8 + 6) * 20 + l16];
                u16 e7 = Vl[(ko * 32 + quad * 8 + 7) * 20 + l16];
                vv.x = (uint32_t)e0 | ((uint32_t)e1 << 16);
                vv.y = (uint32_t)e2 | ((uint32_t)e3 << 16);
                vv.z = (uint32_t)e4 | ((uint32_t)e5 << 16);
                vv.w = (uint32_t)e6 | ((uint32_t)e7 << 16);
            }
            s16x8 vbf = __builtin_bit_cast(s16x8, vv);
            o = __builtin_amdgcn_mfma_f32_16x16x32_bf16(pa, vbf, o, 0, 0, 0);
        }
    }

#pragma unroll
    for (int r = 0; r < 4; ++r) {
        float inv = 1.0f / lr[r];
        int row = q0 + wave * 16 + quad * 4 + r;
        att[((size_t)(b * C_ + row)) * DM_ + h * 16 + l16] = f2bf(o[r] * inv);
    }
}

// ---------------------------------------------------------------- final linear: out = att @ lw^T + lb
// grid = 256 blocks, each 32 rows of the 8192 x 128 output.
__global__ __launch_bounds__(256, 2) void lin_k(
        const u16* __restrict__ att, const float* __restrict__ lw,
        const float* __restrict__ lb, float* __restrict__ out) {
    const int r0 = blockIdx.x * 32;
    __shared__ __align__(16) u16 Wl[128 * 136];
    __shared__ __align__(16) u16 Atl[32 * 136];
    const int tid = threadIdx.x;
    const int wave = tid >> 6, lane = tid & 63;
    const int l16 = lane & 15, quad = lane >> 4;

    {   // stage lin_w -> bf16, layout Wl[j][i]
        int j = tid >> 1, half = tid & 1;
        const float* src = lw + (size_t)j * DM_ + half * 64;
        u16* dstp = &Wl[j * 136 + half * 64];
#pragma unroll
        for (int c = 0; c < 8; ++c) {
            float4 f0 = *(const float4*)(src + c * 8);
            float4 f1 = *(const float4*)(src + c * 8 + 4);
            uint4 p;
            p.x = pk2(f0.x, f0.y); p.y = pk2(f0.z, f0.w);
            p.z = pk2(f1.x, f1.y); p.w = pk2(f1.z, f1.w);
            *(uint4*)(dstp + c * 8) = p;
        }
    }
    {   // stage att tile
        int row = tid >> 3, seg = tid & 7;
        const uint4* src = (const uint4*)(att + ((size_t)(r0 + row)) * DM_ + seg * 16);
        uint4 a0 = src[0], a1 = src[1];
        *(uint4*)&Atl[row * 136 + seg * 16]     = a0;
        *(uint4*)&Atl[row * 136 + seg * 16 + 8] = a1;
    }
    __syncthreads();

    const int wn0 = wave * 32;
    f32x4 acc[2][2];
#pragma unroll
    for (int i = 0; i < 2; ++i)
#pragma unroll
        for (int j = 0; j < 2; ++j) acc[i][j] = (f32x4){0.f, 0.f, 0.f, 0.f};
#pragma unroll
    for (int ko = 0; ko < 4; ++ko) {
        s16x8 af[2], bf[2];
#pragma unroll
        for (int fm = 0; fm < 2; ++fm)
            af[fm] = *(const s16x8*)&Atl[(fm * 16 + l16) * 136 + ko * 32 + quad * 8];
#pragma unroll
        for (int fn = 0; fn < 2; ++fn)
            bf[fn] = *(const s16x8*)&Wl[(wn0 + fn * 16 + l16) * 136 + ko * 32 + quad * 8];
#pragma unroll
        for (int fm = 0; fm < 2; ++fm)
#pragma unroll
            for (int fn = 0; fn < 2; ++fn)
                acc[fm][fn] = __builtin_amdgcn_mfma_f32_16x16x32_bf16(af[fm], bf[fn], acc[fm][fn], 0, 0, 0);
    }
#pragma unroll
    for (int fm = 0; fm < 2; ++fm) {
#pragma unroll
        for (int fn = 0; fn < 2; ++fn) {
            int col = wn0 + fn * 16 + l16;
            float bias = lb[col];
#pragma unroll
            for (int r = 0; r < 4; ++r) {
                int row = r0 + fm * 16 + quad * 4 + r;
                out[(size_t)row * DM_ + col] = acc[fm][fn][r] + bias;
            }
        }
    }
}

// ---------------------------------------------------------------- launcher
extern "C" void kernel_launch(void* const* d_in, const int* in_sizes, int n_in,
                              void* d_out, int out_size, void* d_ws, size_t ws_size,
                              hipStream_t stream) {
    const float* query = (const float*)d_in[0];
    const float* key   = (const float*)d_in[1];
    const float* value = (const float*)d_in[2];
    const float* wk    = (const float*)d_in[3];
    const float* bk    = (const float*)d_in[4];
    const float* wv    = (const float*)d_in[5];
    const float* bv    = (const float*)d_in[6];
    const float* lw    = (const float*)d_in[7];
    const float* lb    = (const float*)d_in[8];
    float* out = (float*)d_out;

    char* ws = (char*)d_ws;
    u16*   bimt_k = (u16*)(ws);                       // 14,680,064 B
    u16*   bimt_v = (u16*)(ws + 14680064);            // 14,680,064 B
    float* yk     = (float*)(ws + 29360128);          // 4 MB
    float* yv     = (float*)(ws + 33554432);          // 4 MB
    u16*   qbf    = (u16*)(ws + 37748736);            // 2 MB
    u16*   att    = (u16*)(ws + 39845888);            // 2 MB   (total ~40 MB)

    // 1) zero conv accumulators (yk & yv are contiguous: 8 MB = 524288 float4)
    zero_f4<<<2048, 256, 0, stream>>>((float4*)yk, 524288);
    // 2) im2col^T bf16 for key & value
    prep_bimt<<<dim3(2048, 1, 2), 256, 0, stream>>>(key, value, bimt_k, bimt_v);
    // 3) query -> bf16 * 0.25
    prep_q<<<1024, 256, 0, stream>>>((const float4*)query, (uint2*)qbf);
    // 4) both convs as split-K GEMM
    conv_gemm<<<dim3(32, 2, 8), 256, 0, stream>>>(wk, wv, bimt_k, bimt_v, yk, yv);
    // 5) flash attention
    attn_k<<<dim3(32, 32), 256, 0, stream>>>(yk, yv, bk, bv, qbf, att);
    // 6) output projection
    lin_k<<<256, 256, 0, stream>>>(att, lw, lb, out);
}

// Round 2
// 483.572 us; speedup vs baseline: 1.2788x; 1.2788x over previous
//
#include <hip/hip_runtime.h>
#include <cstdint>
#include <cstddef>

// Problem constants
#define B_   4
#define C_   2048      // seq / conv channels
#define DM_  128       // d_model / conv length
#define H_   8
#define KK_  14336     // C_ * 7  (im2col K dimension)
#define N_   512       // B_ * DM_ (GEMM N dimension)

#define KSPLIT 8
#define KPB   1792     // KK_ / KSPLIT
#define NITER 56       // KPB / 32

typedef unsigned short u16;
typedef __attribute__((ext_vector_type(8))) short  s16x8;   // 8 x bf16 (4 VGPRs)
typedef __attribute__((ext_vector_type(4))) float  f32x4;

typedef const __attribute__((address_space(1))) void gvoid;
typedef __attribute__((address_space(3))) void lvoid;

__device__ __forceinline__ void gl2lds16(const void* g, void* l) {
    __builtin_amdgcn_global_load_lds((gvoid*)g, (lvoid*)l, 16, 0, 0);
}

__device__ __forceinline__ u16 f2bf(float f) {
    uint32_t u = __builtin_bit_cast(uint32_t, f);
    u += 0x7fffu + ((u >> 16) & 1u);   // round-to-nearest-even
    return (u16)(u >> 16);
}
__device__ __forceinline__ uint32_t pk2(float a, float b) {
    return (uint32_t)f2bf(a) | ((uint32_t)f2bf(b) << 16);
}

// ---------------------------------------------------------------- zero
__global__ __launch_bounds__(256) void zero_f4(float4* __restrict__ p, int n4) {
    int i = blockIdx.x * 256 + threadIdx.x;
    if (i < n4) p[i] = make_float4(0.f, 0.f, 0.f, 0.f);
}

// ---------------------------------------------------------------- im2col^T prep
// BimT[n][k] = x[b][ci][l + t - 6] (0 if <0), n = b*128+l, k = ci*7+t, bf16.
__global__ __launch_bounds__(256) void prep_bimt(const float* __restrict__ key,
                                                 const float* __restrict__ value,
                                                 u16* __restrict__ bk,
                                                 u16* __restrict__ bv) {
    const float* src = blockIdx.z ? value : key;
    u16*         dst = blockIdx.z ? bv : bk;
    int gid = blockIdx.x * 256 + threadIdx.x;   // 0 .. 524287
    int cp = gid & 1023;                        // ci pair index
    int n  = gid >> 10;                         // 0 .. 511
    int b = n >> 7, l = n & 127;
    const float* s0 = src + (size_t)(b * C_ + cp * 2) * DM_;
    u16 hh[14];
#pragma unroll
    for (int r = 0; r < 2; ++r) {
#pragma unroll
        for (int t = 0; t < 7; ++t) {
            int j = l + t - 6;
            float v = (j >= 0) ? s0[r * DM_ + j] : 0.0f;
            hh[r * 7 + t] = f2bf(v);
        }
    }
    uint32_t* D = (uint32_t*)dst + (size_t)n * (KK_ / 2) + cp * 7;
#pragma unroll
    for (int i = 0; i < 7; ++i)
        D[i] = (uint32_t)hh[2 * i] | ((uint32_t)hh[2 * i + 1] << 16);
}

// ---------------------------------------------------------------- query prep (scale 1/4, bf16)
__global__ __launch_bounds__(256) void prep_q(const float4* __restrict__ q, uint2* __restrict__ qb) {
    int i = blockIdx.x * 256 + threadIdx.x;     // 0 .. 262143
    float4 v = q[i];
    uint2 r;
    r.x = pk2(v.x * 0.25f, v.y * 0.25f);
    r.y = pk2(v.z * 0.25f, v.w * 0.25f);
    qb[i] = r;
}

// ---------------------------------------------------------------- conv as GEMM
// Y[m=co][n=(b,l)] += sum_k W[m][k] * BimT[n][k]. Tile 128M x 256N, splitK=8.
// Double-buffered LDS; B staged via global_load_lds (XOR-swizzled source);
// W (fp32) register-prefetched and converted to bf16 in VALU.
// grid: x=16 Mtiles, y=2 Ntiles, z=16 (conv*8 + splitk)
__global__ __launch_bounds__(256, 2) void conv_gemm(
        const float* __restrict__ Wk, const float* __restrict__ Wv,
        const u16* __restrict__ Bk, const u16* __restrict__ Bv,
        float* __restrict__ Yk, float* __restrict__ Yv) {
    const int conv = blockIdx.z >> 3;
    const int sk   = blockIdx.z & 7;
    const float* W  = conv ? Wv : Wk;
    const u16*   Bm = conv ? Bv : Bk;
    float*       Y  = conv ? Yv : Yk;
    const int m0 = blockIdx.x * 128;
    const int n0 = blockIdx.y * 256;
    const int kbeg = sk * KPB;

    __shared__ __align__(16) u16 Al[2][128 * 32];   // 8 KB each, rows 64 B, XOR-swizzled segs
    __shared__ __align__(16) u16 Bl[2][256 * 32];   // 16 KB each

    const int tid = threadIdx.x;
    const int wave = tid >> 6, lane = tid & 63;
    const int l16 = lane & 15, quad = lane >> 4;
    const int wm = wave >> 1, wn = wave & 1;        // wave tile: 64M x 128N

    // ---- A (W) staging: thread covers 64 B (16 fp32) of one row
    const int arow = tid >> 1, ahalf = tid & 1;
    const float* wp = W + (size_t)(m0 + arow) * KK_ + kbeg + ahalf * 16;
    const int asw = (arow >> 1) & 3;
    const int aoff0 = arow * 32 + (((ahalf * 2)     ^ asw) * 8);
    const int aoff1 = arow * 32 + (((ahalf * 2 + 1) ^ asw) * 8);

    // ---- B staging via global_load_lds (4 passes/wave, 16 rows each)
    const u16* bgp[4];
    int boff[4];
    {
        const int br = lane >> 2, bs = lane & 3;
#pragma unroll
        for (int p = 0; p < 4; ++p) {
            int row = wave * 64 + p * 16 + br;
            int gc = (bs ^ ((row >> 1) & 3)) * 8;      // swizzled source chunk
            bgp[p] = Bm + (size_t)(n0 + row) * KK_ + kbeg + gc;
            boff[p] = (wave * 64 + p * 16) * 32;
        }
    }

    f32x4 acc[4][8];
#pragma unroll
    for (int i = 0; i < 4; ++i)
#pragma unroll
        for (int j = 0; j < 8; ++j) acc[i][j] = (f32x4){0.f, 0.f, 0.f, 0.f};

    float4 wr0, wr1, wr2, wr3;
    // ---- prologue: stage tile 0 into buffer 0, prefetch W(1)
    {
        float4 a0 = *(const float4*)(wp);
        float4 a1 = *(const float4*)(wp + 4);
        float4 a2 = *(const float4*)(wp + 8);
        float4 a3 = *(const float4*)(wp + 12);
        uint4 p0, p1;
        p0.x = pk2(a0.x, a0.y); p0.y = pk2(a0.z, a0.w);
        p0.z = pk2(a1.x, a1.y); p0.w = pk2(a1.z, a1.w);
        p1.x = pk2(a2.x, a2.y); p1.y = pk2(a2.z, a2.w);
        p1.z = pk2(a3.x, a3.y); p1.w = pk2(a3.z, a3.w);
        *(uint4*)&Al[0][aoff0] = p0;
        *(uint4*)&Al[0][aoff1] = p1;
#pragma unroll
        for (int p = 0; p < 4; ++p)
            gl2lds16(bgp[p], &Bl[0][boff[p]]);
        wr0 = *(const float4*)(wp + 32);
        wr1 = *(const float4*)(wp + 36);
        wr2 = *(const float4*)(wp + 40);
        wr3 = *(const float4*)(wp + 44);
    }

    int c = 0;
    for (int ks = 0; ks < NITER; ++ks) {
        __syncthreads();   // drains tile-ks loads into buf c; orders prev readers of c^1
        // frag reads FIRST (no outstanding LDS-DMA targets them now)
        s16x8 af[4];
#pragma unroll
        for (int fm = 0; fm < 4; ++fm) {
            int r = wm * 64 + fm * 16 + l16;
            af[fm] = *(const s16x8*)&Al[c][r * 32 + ((quad ^ ((r >> 1) & 3)) * 8)];
        }
        s16x8 bfr[4];
#pragma unroll
        for (int fn = 0; fn < 4; ++fn) {
            int n = wn * 128 + fn * 16 + l16;
            bfr[fn] = *(const s16x8*)&Bl[c][n * 32 + ((quad ^ ((n >> 1) & 3)) * 8)];
        }
        // prefetch next tile into buf c^1 (lands by next barrier)
        const int kn  = (ks + 1 < NITER) ? ks + 1 : ks;
        const int kn2 = (ks + 2 < NITER) ? ks + 2 : 0;
#pragma unroll
        for (int p = 0; p < 4; ++p)
            gl2lds16(bgp[p] + (size_t)kn * 32, &Bl[c ^ 1][boff[p]]);
        {
            uint4 p0, p1;
            p0.x = pk2(wr0.x, wr0.y); p0.y = pk2(wr0.z, wr0.w);
            p0.z = pk2(wr1.x, wr1.y); p0.w = pk2(wr1.z, wr1.w);
            p1.x = pk2(wr2.x, wr2.y); p1.y = pk2(wr2.z, wr2.w);
            p1.z = pk2(wr3.x, wr3.y); p1.w = pk2(wr3.z, wr3.w);
            *(uint4*)&Al[c ^ 1][aoff0] = p0;
            *(uint4*)&Al[c ^ 1][aoff1] = p1;
        }
        wr0 = *(const float4*)(wp + (size_t)kn2 * 32);
        wr1 = *(const float4*)(wp + (size_t)kn2 * 32 + 4);
        wr2 = *(const float4*)(wp + (size_t)kn2 * 32 + 8);
        wr3 = *(const float4*)(wp + (size_t)kn2 * 32 + 12);
        // MFMA on buffer c (first N-half)
#pragma unroll
        for (int fm = 0; fm < 4; ++fm)
#pragma unroll
            for (int fn = 0; fn < 4; ++fn)
                acc[fm][fn] = __builtin_amdgcn_mfma_f32_16x16x32_bf16(af[fm], bfr[fn], acc[fm][fn], 0, 0, 0);
        // second N-half
#pragma unroll
        for (int fn = 0; fn < 4; ++fn) {
            int n = wn * 128 + (fn + 4) * 16 + l16;
            bfr[fn] = *(const s16x8*)&Bl[c][n * 32 + ((quad ^ ((n >> 1) & 3)) * 8)];
        }
#pragma unroll
        for (int fm = 0; fm < 4; ++fm)
#pragma unroll
            for (int fn = 0; fn < 4; ++fn)
                acc[fm][fn + 4] = __builtin_amdgcn_mfma_f32_16x16x32_bf16(af[fm], bfr[fn], acc[fm][fn + 4], 0, 0, 0);
        c ^= 1;
    }

    // epilogue: split-K accumulate. C layout: col = lane&15, row = quad*4 + reg.
#pragma unroll
    for (int fm = 0; fm < 4; ++fm) {
        int m = m0 + wm * 64 + fm * 16 + quad * 4;
#pragma unroll
        for (int fn = 0; fn < 8; ++fn) {
            int n = n0 + wn * 128 + fn * 16 + l16;
            int bb = n >> 7, ll = n & 127;
            float* yp = Y + ((size_t)(bb * C_ + m)) * DM_ + ll;
#pragma unroll
            for (int r = 0; r < 4; ++r)
                atomicAdd(yp + (size_t)r * DM_, acc[fm][fn][r]);
        }
    }
}

// ---------------------------------------------------------------- K/V prep for attention
// Kbf[bh][key][d16] = bf16(Yk + bias) ; Vbf[bh][d16][key] = bf16(Yv + bias) (transposed)
__global__ __launch_bounds__(256) void kv_prep(
        const float* __restrict__ Yk, const float* __restrict__ Yv,
        const float* __restrict__ bkb, const float* __restrict__ bvb,
        u16* __restrict__ Kbf, u16* __restrict__ Vbf) {
    int gid = blockIdx.x * 256 + threadIdx.x;   // 0 .. 65535
    int key = gid & 2047;
    int bh  = gid >> 11;
    int b = bh >> 3, h = bh & 7;
    size_t src = ((size_t)(b * C_ + key)) * DM_ + h * 16;
    float kb = bkb[key], vb = bvb[key];

    float4 k0 = *(const float4*)(Yk + src);
    float4 k1 = *(const float4*)(Yk + src + 4);
    float4 k2 = *(const float4*)(Yk + src + 8);
    float4 k3 = *(const float4*)(Yk + src + 12);
    uint4 pA, pB;
    pA.x = pk2(k0.x + kb, k0.y + kb); pA.y = pk2(k0.z + kb, k0.w + kb);
    pA.z = pk2(k1.x + kb, k1.y + kb); pA.w = pk2(k1.z + kb, k1.w + kb);
    pB.x = pk2(k2.x + kb, k2.y + kb); pB.y = pk2(k2.z + kb, k2.w + kb);
    pB.z = pk2(k3.x + kb, k3.y + kb); pB.w = pk2(k3.z + kb, k3.w + kb);
    u16* kd = Kbf + ((size_t)bh * C_ + key) * 16;
    *(uint4*)kd       = pA;
    *(uint4*)(kd + 8) = pB;

    float4 v0 = *(const float4*)(Yv + src);
    float4 v1 = *(const float4*)(Yv + src + 4);
    float4 v2 = *(const float4*)(Yv + src + 8);
    float4 v3 = *(const float4*)(Yv + src + 12);
    float vf[16] = {v0.x, v0.y, v0.z, v0.w, v1.x, v1.y, v1.z, v1.w,
                    v2.x, v2.y, v2.z, v2.w, v3.x, v3.y, v3.z, v3.w};
    u16* vdst = Vbf + (size_t)bh * 16 * C_ + key;
#pragma unroll
    for (int d = 0; d < 16; ++d)
        vdst[(size_t)d * C_] = f2bf(vf[d] + vb);   // coalesced across lanes (key fastest)
}

// ---------------------------------------------------------------- flash attention
// grid: x = 32 q-tiles (64 rows), y = 32 (b*8+h). Block 256 = 4 waves; wave owns 16 q-rows.
__global__ __launch_bounds__(256, 4) void attn_k(
        const u16* __restrict__ Kbf, const u16* __restrict__ Vbf,
        const u16* __restrict__ qb, u16* __restrict__ att) {
    const int q0 = blockIdx.x * 64;
    const int bh = blockIdx.y;
    const int b = bh >> 3, h = bh & 7;

    __shared__ __align__(16) u16 Kl[128 * 24];   // key rows x 16 d, padded to 48 B
    __shared__ __align__(16) u16 Vl[16 * 128];   // d rows x 128 keys, chunk-swizzled
    __shared__ __align__(16) u16 Pl[64 * 136];   // q rows x 128 keys

    const int tid = threadIdx.x;
    const int wave = tid >> 6, lane = tid & 63;
    const int l16 = lane & 15, quad = lane >> 4;
    const float LOG2E = 1.44269504088896340736f;

    // K staging (manual, padded rows): thread covers 16 B of one key row
    const u16* kgp = Kbf + ((size_t)bh * C_ + (tid >> 1)) * 16 + (tid & 1) * 8;
    u16* kld = &Kl[(tid >> 1) * 24 + (tid & 1) * 8];
    // V staging via global_load_lds: lane: d = wave*4 + (lane>>4), chunk = lane&15 (swizzled source)
    const int vd = wave * 4 + (lane >> 4);
    const u16* vgp = Vbf + ((size_t)bh * 16 + vd) * C_ + (size_t)(((lane & 15) ^ (vd & 7)) * 8);
    u16* vld = &Vl[wave * 4 * 128];

    // Q fragment (A-layout): m = lane&15, k(d) = quad*8+j ; d>=16 zero padding.
    s16x8 qf = {};
    if (quad < 2) {
        const u16* qp = qb + ((size_t)(b * C_ + q0 + wave * 16 + l16)) * DM_ + h * 16 + quad * 8;
        qf = *(const s16x8*)qp;
    }
    f32x4 o = (f32x4){0.f, 0.f, 0.f, 0.f};
    float mr[4] = {-3e38f, -3e38f, -3e38f, -3e38f};
    float lr[4] = {0.f, 0.f, 0.f, 0.f};

    for (int kt = 0; kt < 16; ++kt) {
        const int k0 = kt * 128;
        __syncthreads();                       // prev PV reads of Vl done
        {
            uint4 kv = *(const uint4*)(kgp + (size_t)k0 * 16);
            *(uint4*)kld = kv;
            gl2lds16(vgp + k0, vld);
        }
        __syncthreads();                       // K/V staged (drains LDS-DMA too)

        // S = Q K^T : 8 N-frags of 16 keys
        f32x4 sf[8];
#pragma unroll
        for (int fn = 0; fn < 8; ++fn) {
            s16x8 kb = {};
            if (quad < 2) kb = *(const s16x8*)&Kl[(fn * 16 + l16) * 24 + quad * 8];
            sf[fn] = __builtin_amdgcn_mfma_f32_16x16x32_bf16(qf, kb, (f32x4){0.f, 0.f, 0.f, 0.f}, 0, 0, 0);
        }

        // online softmax: lane holds rows quad*4+r, cols l16 + 16*fn
        float mt[4];
#pragma unroll
        for (int r = 0; r < 4; ++r) {
            float m = sf[0][r];
#pragma unroll
            for (int fn = 1; fn < 8; ++fn) m = fmaxf(m, sf[fn][r]);
            m = fmaxf(m, __shfl_xor(m, 1));
            m = fmaxf(m, __shfl_xor(m, 2));
            m = fmaxf(m, __shfl_xor(m, 4));
            m = fmaxf(m, __shfl_xor(m, 8));
            mt[r] = m;
        }
        float al[4], ps[4];
#pragma unroll
        for (int r = 0; r < 4; ++r) {
            float mnew = fmaxf(mr[r], mt[r]);
            al[r] = exp2f((mr[r] - mnew) * LOG2E);
            mr[r] = mnew;
            ps[r] = 0.f;
        }
#pragma unroll
        for (int fn = 0; fn < 8; ++fn) {
#pragma unroll
            for (int r = 0; r < 4; ++r) {
                float p = exp2f((sf[fn][r] - mr[r]) * LOG2E);
                ps[r] += p;
                Pl[(wave * 16 + quad * 4 + r) * 136 + fn * 16 + l16] = f2bf(p);
            }
        }
#pragma unroll
        for (int r = 0; r < 4; ++r) {
            float t = ps[r];
            t += __shfl_xor(t, 1);
            t += __shfl_xor(t, 2);
            t += __shfl_xor(t, 4);
            t += __shfl_xor(t, 8);
            lr[r] = lr[r] * al[r] + t;
            o[r] *= al[r];
        }
        // Pl region is wave-private: same-wave ds_write -> ds_read needs no barrier.
        // O += P V  (K-dim = 128 keys, 4 MFMAs)
#pragma unroll
        for (int ko = 0; ko < 4; ++ko) {
            s16x8 pa = *(const s16x8*)&Pl[(wave * 16 + l16) * 136 + ko * 32 + quad * 8];
            s16x8 vb = *(const s16x8*)&Vl[l16 * 128 + (((ko * 4 + quad) ^ (l16 & 7)) * 8)];
            o = __builtin_amdgcn_mfma_f32_16x16x32_bf16(pa, vb, o, 0, 0, 0);
        }
    }

#pragma unroll
    for (int r = 0; r < 4; ++r) {
        float inv = 1.0f / lr[r];
        int row = q0 + wave * 16 + quad * 4 + r;
        att[((size_t)(b * C_ + row)) * DM_ + h * 16 + l16] = f2bf(o[r] * inv);
    }
}

// ---------------------------------------------------------------- final linear: out = att @ lw^T + lb
__global__ __launch_bounds__(256, 2) void lin_k(
        const u16* __restrict__ att, const float* __restrict__ lw,
        const float* __restrict__ lb, float* __restrict__ out) {
    const int r0 = blockIdx.x * 32;
    __shared__ __align__(16) u16 Wl[128 * 136];
    __shared__ __align__(16) u16 Atl[32 * 136];
    const int tid = threadIdx.x;
    const int wave = tid >> 6, lane = tid & 63;
    const int l16 = lane & 15, quad = lane >> 4;

    {   // stage lin_w -> bf16, layout Wl[j][i]
        int j = tid >> 1, half = tid & 1;
        const float* src = lw + (size_t)j * DM_ + half * 64;
        u16* dstp = &Wl[j * 136 + half * 64];
#pragma unroll
        for (int c = 0; c < 8; ++c) {
            float4 f0 = *(const float4*)(src + c * 8);
            float4 f1 = *(const float4*)(src + c * 8 + 4);
            uint4 p;
            p.x = pk2(f0.x, f0.y); p.y = pk2(f0.z, f0.w);
            p.z = pk2(f1.x, f1.y); p.w = pk2(f1.z, f1.w);
            *(uint4*)(dstp + c * 8) = p;
        }
    }
    {   // stage att tile
        int row = tid >> 3, seg = tid & 7;
        const uint4* src = (const uint4*)(att + ((size_t)(r0 + row)) * DM_ + seg * 16);
        uint4 a0 = src[0], a1 = src[1];
        *(uint4*)&Atl[row * 136 + seg * 16]     = a0;
        *(uint4*)&Atl[row * 136 + seg * 16 + 8] = a1;
    }
    __syncthreads();

    const int wn0 = wave * 32;
    f32x4 acc[2][2];
#pragma unroll
    for (int i = 0; i < 2; ++i)
#pragma unroll
        for (int j = 0; j < 2; ++j) acc[i][j] = (f32x4){0.f, 0.f, 0.f, 0.f};
#pragma unroll
    for (int ko = 0; ko < 4; ++ko) {
        s16x8 af[2], bf[2];
#pragma unroll
        for (int fm = 0; fm < 2; ++fm)
            af[fm] = *(const s16x8*)&Atl[(fm * 16 + l16) * 136 + ko * 32 + quad * 8];
#pragma unroll
        for (int fn = 0; fn < 2; ++fn)
            bf[fn] = *(const s16x8*)&Wl[(wn0 + fn * 16 + l16) * 136 + ko * 32 + quad * 8];
#pragma unroll
        for (int fm = 0; fm < 2; ++fm)
#pragma unroll
            for (int fn = 0; fn < 2; ++fn)
                acc[fm][fn] = __builtin_amdgcn_mfma_f32_16x16x32_bf16(af[fm], bf[fn], acc[fm][fn], 0, 0, 0);
    }
#pragma unroll
    for (int fm = 0; fm < 2; ++fm) {
#pragma unroll
        for (int fn = 0; fn < 2; ++fn) {
            int col = wn0 + fn * 16 + l16;
            float bias = lb[col];
#pragma unroll
            for (int r = 0; r < 4; ++r) {
                int row = r0 + fm * 16 + quad * 4 + r;
                out[(size_t)row * DM_ + col] = acc[fm][fn][r] + bias;
            }
        }
    }
}

// ---------------------------------------------------------------- launcher
extern "C" void kernel_launch(void* const* d_in, const int* in_sizes, int n_in,
                              void* d_out, int out_size, void* d_ws, size_t ws_size,
                              hipStream_t stream) {
    const float* query = (const float*)d_in[0];
    const float* key   = (const float*)d_in[1];
    const float* value = (const float*)d_in[2];
    const float* wk    = (const float*)d_in[3];
    const float* bk    = (const float*)d_in[4];
    const float* wv    = (const float*)d_in[5];
    const float* bv    = (const float*)d_in[6];
    const float* lw    = (const float*)d_in[7];
    const float* lb    = (const float*)d_in[8];
    float* out = (float*)d_out;

    char* ws = (char*)d_ws;
    u16*   bimt_k = (u16*)(ws);                       // 14,680,064 B
    u16*   bimt_v = (u16*)(ws + 14680064);            // 14,680,064 B
    float* yk     = (float*)(ws + 29360128);          // 4 MB
    float* yv     = (float*)(ws + 33554432);          // 4 MB
    u16*   qbf    = (u16*)(ws + 37748736);            // 2 MB
    u16*   att    = (u16*)(ws + 39845888);            // 2 MB
    u16*   kbf    = (u16*)(ws + 41943040);            // 2 MB
    u16*   vbf    = (u16*)(ws + 44040192);            // 2 MB  (total ~44 MB)

    // 1) zero conv accumulators (yk & yv contiguous: 8 MB = 524288 float4)
    zero_f4<<<2048, 256, 0, stream>>>((float4*)yk, 524288);
    // 2) im2col^T bf16 for key & value
    prep_bimt<<<dim3(2048, 1, 2), 256, 0, stream>>>(key, value, bimt_k, bimt_v);
    // 3) query -> bf16 * 0.25
    prep_q<<<1024, 256, 0, stream>>>((const float4*)query, (uint2*)qbf);
    // 4) both convs as split-K GEMM (pipelined, global_load_lds)
    conv_gemm<<<dim3(16, 2, 16), 256, 0, stream>>>(wk, wv, bimt_k, bimt_v, yk, yv);
    // 5) bias + bf16 + transpose prep for attention K/V
    kv_prep<<<256, 256, 0, stream>>>(yk, yv, bk, bv, kbf, vbf);
    // 6) flash attention
    attn_k<<<dim3(32, 32), 256, 0, stream>>>(kbf, vbf, qbf, att);
    // 7) output projection
    lin_k<<<256, 256, 0, stream>>>(att, lw, lb, out);
}